// Round 1
// baseline (308.399 us; speedup 1.0000x reference)
//
#include <hip/hip_runtime.h>
#include <stdint.h>

#define SEQ 1024
#define BATCH 512
#define NTAGS 64
#define HALF_T 512
#define LOGD 4.158883083f   // log(64): per-step damp folded into exp(em)

typedef _Float16 v2h   __attribute__((ext_vector_type(2)));
typedef float    f32x4 __attribute__((ext_vector_type(4)));

__device__ __forceinline__ float dot2acc(v2h a, v2h b, float c) {
#if __has_builtin(__builtin_amdgcn_fdot2)
    return __builtin_amdgcn_fdot2(a, b, c, false);
#else
    return fmaf((float)a.x, (float)b.x, fmaf((float)a.y, (float)b.y, c));
#endif
}

__device__ __forceinline__ float rfl(float x) {
    return __uint_as_float(__builtin_amdgcn_readfirstlane(__float_as_uint(x)));
}

__device__ __forceinline__ v2h bch(float f) { return __builtin_bit_cast(v2h, f); }

// Fused CRF kernel: block b runs BOTH chains of batch b.
//   wave0 (fwd): t = 1..min(L-1,511), keeps beta_f in regs.
//   wave1 (bwd): t = L-1..512 descending, publishes gamma/Mb via LDS.
// Then both waves compute the numerator partials and wave0 joins.
// DOT is a hand-scheduled asm block: ds_write_b16 + 8x ds_read_b128 with
// staged lgkmcnt(4)/lgkmcnt(0) — relies on the in-order DS pipe for the
// same-wave RAW (write -> reads), avoiding the compiler's full drain.
__global__ __launch_bounds__(128)
void crf_kernel(const float* __restrict__ em,
                const int* __restrict__ tags,
                const int* __restrict__ mask,
                const float* __restrict__ startT,
                const float* __restrict__ endT,
                const float* __restrict__ trans,
                float* __restrict__ out)
{
    const int  b   = blockIdx.x;
    const int  wid = threadIdx.x >> 6;
    const int  j   = threadIdx.x & 63;
    const bool fwd = (wid == 0);

    __shared__ __align__(16) _Float16 bsh[2][NTAGS];  // per-wave broadcast buffer
    __shared__ float gsh[NTAGS];                      // gamma from bwd wave
    __shared__ float mb_np[2];                        // [0]=Mb, [1]=np partial (bwd)

    // LDS byte offset of this wave's buffer (generic LDS ptr: low 32 bits = ds offset)
    const unsigned lbase = (unsigned)(uintptr_t)(&bsh[wid][0]);
    const unsigned wa    = lbase + 2u * (unsigned)j;  // per-lane write addr
    const unsigned ra    = lbase;                     // uniform read base

    // chain length = sum of this batch's mask column
    int lsum = 0;
#pragma unroll
    for (int k = 0; k < SEQ / 64; ++k)
        lsum += mask[(k * 64 + j) * BATCH + b];
#pragma unroll
    for (int off = 32; off > 0; off >>= 1)
        lsum += __shfl_xor(lsum, off);
    const int L = lsum;

    // fp16 expT fragment: fwd lane j = column j (paired over i);
    // bwd lane j = row j (paired over k).
    v2h w[32];
#pragma unroll
    for (int i = 0; i < 32; ++i) {
        float a0, a1;
        if (fwd) { a0 = trans[(2 * i) * NTAGS + j]; a1 = trans[(2 * i + 1) * NTAGS + j]; }
        else     { a0 = trans[j * NTAGS + 2 * i];   a1 = trans[j * NTAGS + 2 * i + 1];   }
        v2h t; t.x = (_Float16)__expf(a0); t.y = (_Float16)__expf(a1);
        w[i] = t;
    }

// Hand-scheduled broadcast + dot. 9 DS ops outstanding after issue:
// lgkmcnt(4) => write + q0..q3 retired (DS completes in order) -> start dots;
// second wait releases q4..q7 ("+v" ties + sched_barrier(0) per rule #18).
#define DOT(WRVAL, SOUT)                                                         \
    {                                                                            \
        f32x4 q0, q1, q2, q3, q4, q5, q6, q7;                                    \
        float vtmp;                                                              \
        asm volatile(                                                            \
            "v_cvt_f16_f32 %[t], %[v]\n\t"                                       \
            "ds_write_b16 %[wa], %[t]\n\t"                                       \
            "ds_read_b128 %[a0], %[ra] offset:0\n\t"                             \
            "ds_read_b128 %[a1], %[ra] offset:16\n\t"                            \
            "ds_read_b128 %[a2], %[ra] offset:32\n\t"                            \
            "ds_read_b128 %[a3], %[ra] offset:48\n\t"                            \
            "ds_read_b128 %[a4], %[ra] offset:64\n\t"                            \
            "ds_read_b128 %[a5], %[ra] offset:80\n\t"                            \
            "ds_read_b128 %[a6], %[ra] offset:96\n\t"                            \
            "ds_read_b128 %[a7], %[ra] offset:112\n\t"                           \
            "s_waitcnt lgkmcnt(4)"                                               \
            : [a0] "=&v"(q0), [a1] "=&v"(q1), [a2] "=&v"(q2), [a3] "=&v"(q3),    \
              [a4] "=&v"(q4), [a5] "=&v"(q5), [a6] "=&v"(q6), [a7] "=&v"(q7),    \
              [t] "=&v"(vtmp)                                                    \
            : [v] "v"(WRVAL), [wa] "v"(wa), [ra] "v"(ra));                       \
        __builtin_amdgcn_sched_barrier(0);                                       \
        float s0 = 0.f, s1 = 0.f, s2 = 0.f, s3 = 0.f;                            \
        s0 = dot2acc(bch(q0.x), w[0],  s0);                                      \
        s1 = dot2acc(bch(q1.x), w[4],  s1);                                      \
        s2 = dot2acc(bch(q2.x), w[8],  s2);                                      \
        s3 = dot2acc(bch(q3.x), w[12], s3);                                      \
        s0 = dot2acc(bch(q0.y), w[1],  s0);                                      \
        s1 = dot2acc(bch(q1.y), w[5],  s1);                                      \
        s2 = dot2acc(bch(q2.y), w[9],  s2);                                      \
        s3 = dot2acc(bch(q3.y), w[13], s3);                                      \
        s0 = dot2acc(bch(q0.z), w[2],  s0);                                      \
        s1 = dot2acc(bch(q1.z), w[6],  s1);                                      \
        s2 = dot2acc(bch(q2.z), w[10], s2);                                      \
        s3 = dot2acc(bch(q3.z), w[14], s3);                                      \
        s0 = dot2acc(bch(q0.w), w[3],  s0);                                      \
        s1 = dot2acc(bch(q1.w), w[7],  s1);                                      \
        s2 = dot2acc(bch(q2.w), w[11], s2);                                      \
        s3 = dot2acc(bch(q3.w), w[15], s3);                                      \
        asm volatile("s_waitcnt lgkmcnt(0)"                                      \
                     : "+v"(q4), "+v"(q5), "+v"(q6), "+v"(q7));                  \
        __builtin_amdgcn_sched_barrier(0);                                       \
        float s4 = 0.f, s5 = 0.f, s6 = 0.f, s7 = 0.f;                            \
        s4 = dot2acc(bch(q4.x), w[16], s4);                                      \
        s5 = dot2acc(bch(q5.x), w[20], s5);                                      \
        s6 = dot2acc(bch(q6.x), w[24], s6);                                      \
        s7 = dot2acc(bch(q7.x), w[28], s7);                                      \
        s4 = dot2acc(bch(q4.y), w[17], s4);                                      \
        s5 = dot2acc(bch(q5.y), w[21], s5);                                      \
        s6 = dot2acc(bch(q6.y), w[25], s6);                                      \
        s7 = dot2acc(bch(q7.y), w[29], s7);                                      \
        s4 = dot2acc(bch(q4.z), w[18], s4);                                      \
        s5 = dot2acc(bch(q5.z), w[22], s5);                                      \
        s6 = dot2acc(bch(q6.z), w[26], s6);                                      \
        s7 = dot2acc(bch(q7.z), w[30], s7);                                      \
        s4 = dot2acc(bch(q4.w), w[19], s4);                                      \
        s5 = dot2acc(bch(q5.w), w[23], s5);                                      \
        s6 = dot2acc(bch(q6.w), w[27], s6);                                      \
        s7 = dot2acc(bch(q7.w), w[31], s7);                                      \
        SOUT = ((s0 + s1) + (s2 + s3)) + ((s4 + s5) + (s6 + s7));                \
    }

    float beta, M;
    int nsteps = 0;

    if (fwd) {
        float em0 = em[(size_t)b * NTAGS + j];
        float a0  = startT[j] + em0;
        M    = __shfl(a0, 0);
        beta = __expf(a0 - M);

        const int Lf = min(L - 1, HALF_T - 1);   // active steps t=1..Lf
        int t = 1;
        float cur[4], nxt[4];
#pragma unroll
        for (int u = 0; u < 4; ++u) {
            cur[u] = em[((size_t)min(t + u,     SEQ - 1) * BATCH + b) * NTAGS + j];
            nxt[u] = em[((size_t)min(t + 4 + u, SEQ - 1) * BATCH + b) * NTAGS + j];
        }
        while (t + 3 <= Lf) {
            float pre[4];
#pragma unroll
            for (int u = 0; u < 4; ++u)
                pre[u] = em[((size_t)min(t + 8 + u, SEQ - 1) * BATCH + b) * NTAGS + j];
            float eem[4];
#pragma unroll
            for (int u = 0; u < 4; ++u) eem[u] = __expf(cur[u] - LOGD);

            float s;
            DOT(beta, s); beta = s * eem[0];
            DOT(beta, s);
            float r = rfl(s);                 // uniform, ~Sigma(beta): renorm scale
            beta = s * eem[1];
            DOT(beta, s); beta = s * eem[2];
            float rinv = 1.0f / r;            // off-path
            float lr   = __logf(r);           // off-path
            DOT(beta, s); beta = s * (eem[3] * rinv);
            M += lr;
            nsteps += 4;
#pragma unroll
            for (int u = 0; u < 4; ++u) { cur[u] = nxt[u]; nxt[u] = pre[u]; }
            t += 4;
        }
        for (; t <= Lf; ++t) {
            float emt = em[((size_t)t * BATCH + b) * NTAGS + j];
            float s; DOT(beta, s);
            beta = s * __expf(emt - LOGD);
            ++nsteps;
        }
    } else {
        beta = __expf(endT[j]);               // B_j init (frozen for t >= L)
        M = 0.0f;
        if (L - 1 >= HALF_T) {
            int tt = L - 1;                   // steps tt = L-1 .. 512 descending
            float cur[4], nxt[4];
#pragma unroll
            for (int u = 0; u < 4; ++u) {
                cur[u] = em[((size_t)max(tt - u,     0) * BATCH + b) * NTAGS + j];
                nxt[u] = em[((size_t)max(tt - 4 - u, 0) * BATCH + b) * NTAGS + j];
            }
            while (tt - 3 >= HALF_T) {
                float pre[4];
#pragma unroll
                for (int u = 0; u < 4; ++u)
                    pre[u] = em[((size_t)max(tt - 8 - u, 0) * BATCH + b) * NTAGS + j];
                float eem[4];
#pragma unroll
                for (int u = 0; u < 4; ++u) eem[u] = __expf(cur[u] - LOGD);

                float s;
                DOT(beta * eem[0], s); beta = s;
                DOT(beta * eem[1], s);
                float r = rfl(s);
                beta = s;
                DOT(beta * eem[2], s); beta = s;
                float rinv = 1.0f / r;
                float lr   = __logf(r);
                DOT(beta * (eem[3] * rinv), s); beta = s;
                M += lr;
                nsteps += 4;
#pragma unroll
                for (int u = 0; u < 4; ++u) { cur[u] = nxt[u]; nxt[u] = pre[u]; }
                tt -= 4;
            }
            for (; tt >= HALF_T; --tt) {
                float emt = em[((size_t)tt * BATCH + b) * NTAGS + j];
                float s; DOT(beta * __expf(emt - LOGD), s);
                beta = s;
                ++nsteps;
            }
        }
    }
#undef DOT

    const float Mfb = fmaf((float)nsteps, LOGD, M);  // per-wave log-scale

    if (!fwd) {
        gsh[j] = beta;                      // gamma vector
        if (j == 0) mb_np[0] = Mfb;         // Mb
    }

    // numerator partial: thread tid handles t = k*128 + tid
    float np = 0.0f;
#pragma unroll
    for (int k = 0; k < SEQ / 128; ++k) {
        int t = k * 128 + wid * 64 + j;
        if (t >= 1 && t < L) {
            int ct = tags[t * BATCH + b];
            int pt = tags[(t - 1) * BATCH + b];
            np += trans[pt * NTAGS + ct] + em[((size_t)t * BATCH + b) * NTAGS + ct];
        }
    }
    if (threadIdx.x == 0) {
        int t0 = tags[b];
        np += startT[t0] + em[(size_t)b * NTAGS + t0]
            + endT[tags[(size_t)(L - 1) * BATCH + b]];
    }
#pragma unroll
    for (int off = 32; off > 0; off >>= 1)
        np += __shfl_xor(np, off);
    if (!fwd && j == 0) mb_np[1] = np;

    __syncthreads();

    if (fwd) {
        float p = beta * gsh[j];            // midpoint dot: beta_f . gamma
#pragma unroll
        for (int off = 32; off > 0; off >>= 1)
            p += __shfl_xor(p, off);
        if (j == 0) {
            float denom = __logf(p) + Mfb + mb_np[0];
            atomicAdd(out, (np + mb_np[1]) - denom);
        }
    }
}

extern "C" void kernel_launch(void* const* d_in, const int* in_sizes, int n_in,
                              void* d_out, int out_size, void* d_ws, size_t ws_size,
                              hipStream_t stream)
{
    const float* em     = (const float*)d_in[0];
    const int*   tags   = (const int*)d_in[1];
    const int*   mask   = (const int*)d_in[2];
    const float* startT = (const float*)d_in[3];
    const float* endT   = (const float*)d_in[4];
    const float* trans  = (const float*)d_in[5];
    float*       out    = (float*)d_out;

    (void)d_ws; (void)ws_size;

    hipMemsetAsync(out, 0, sizeof(float) * out_size, stream);
    crf_kernel<<<BATCH, 128, 0, stream>>>(em, tags, mask, startT, endT, trans, out);
}